// Round 5
// baseline (193.428 us; speedup 1.0000x reference)
//
#include <hip/hip_runtime.h>
#include <math.h>

// Problem constants (B=2, L=2048, H=16, D=64, HID=1024, NB=4)
#define NBL   4096      // B*L
#define NPOS  65536     // B*L*H
#define TWO_D 128
#define HIDN  1024

typedef __attribute__((ext_vector_type(8))) short short8;  // 8 bf16 (4 VGPRs)
typedef __attribute__((ext_vector_type(4))) float f32x4;   // MFMA accumulator

// fp32 -> bf16, round-to-nearest-even (finite inputs)
__device__ inline short f2bf(float f) {
    union { float f; unsigned u; } v; v.f = f;
    unsigned r = (v.u + 0x7FFFu + ((v.u >> 16) & 1u)) >> 16;
    return (short)r;
}

// ws layout (bytes):
//   hidT : float [4096][128]                      @ 0         (2,097,152)
//   WhT  : bf16  [128][1024]                      @ 2097152   (262,144)
//   WbT  : bf16  [128][256]                       @ 2359296   (65,536)
//   wsT  : bf16  [128][32]                        @ 2424832   (8,192)
//   bB   : bf16  [4][65536][64]                   @ 2433024   (33,554,432)
//   st   : float [65536][12]                      @ 35987456  (3,145,728)
#define WS_NEED 39133184ull

// ---------------------------------------------------------------- K0: weight prep
__global__ __launch_bounds__(256) void k_prep(const float* __restrict__ W1,
                                              short* __restrict__ WhT,
                                              short* __restrict__ WbT,
                                              short* __restrict__ wsT) {
    __shared__ float lds[16][129];
    __shared__ float acc2[128];
    const int b = blockIdx.x, t = threadIdx.x;
    if (b < 80) {
        int srcRow0, dstKD, kofs; short* dst;
        if (b < 64) { srcRow0 = b * 16;               dst = WhT; dstKD = 1024; kofs = b * 16; }
        else        { srcRow0 = 1792 + (b - 64) * 16; dst = WbT; dstKD = 256;  kofs = (b - 64) * 16; }
        #pragma unroll
        for (int i = 0; i < 8; ++i) {
            const int idx = i * 256 + t;
            const int row = idx >> 7, col = idx & 127;
            lds[row][col] = W1[(size_t)(srcRow0 + row) * TWO_D + col];   // coalesced
        }
        __syncthreads();
        #pragma unroll
        for (int i = 0; i < 8; ++i) {
            const int idx = i * 256 + t;
            const int n = idx >> 4, k = idx & 15;
            dst[(size_t)n * dstKD + kofs + k] = f2bf(lds[k][n]);
        }
    } else {
        const int i = b - 80;                       // 0..11
        const int j = i / 3, sx = i - 3 * j;
        const int base = HIDN + j * 192 + sx * 64;
        const int n = t & 127, dh = t >> 7;
        float s = 0.f;
        for (int d = 0; d < 32; ++d)
            s += W1[(size_t)(base + dh * 32 + d) * TWO_D + n];  // coalesced
        if (dh) acc2[n] = s;
        __syncthreads();
        if (!dh) {
            wsT[n * 32 + i] = f2bf(s + acc2[n]);
            if (i == 0)
                for (int p = 12; p < 32; ++p) wsT[n * 32 + p] = (short)0;
        }
    }
}

// ---------------------------------------------------------------- K1: stream convert + stats
// 8192 blocks x 256 thr. 8 threads per 64-elem row: fp32 -> bf16 copy + mean/rms/max.
// XCD-contiguous swizzle: each XCD covers a contiguous quarter-branch slice.
__global__ __launch_bounds__(256) void k_cvt(const float* __restrict__ g0,
                                             const float* __restrict__ g1,
                                             const float* __restrict__ g2,
                                             const float* __restrict__ g3,
                                             short* __restrict__ bB,
                                             float* __restrict__ st) {
    const int b   = blockIdx.x;
    const int bsw = (b & 7) * 1024 + (b >> 3);      // 0..8191, XCD-contiguous
    const int j   = bsw >> 11;                      // branch 0..3
    const int rg  = bsw & 2047;
    const int t   = threadIdx.x;
    const int row = rg * 32 + (t >> 3);             // pos 0..65535
    const int sub = t & 7;
    const float* __restrict__ bp = (j == 0) ? g0 : (j == 1) ? g1 : (j == 2) ? g2 : g3;

    const float4 v0 = *(const float4*)(bp + (size_t)row * 64 + sub * 8);
    const float4 v1 = *(const float4*)(bp + (size_t)row * 64 + sub * 8 + 4);
    short8 o;
    o[0] = f2bf(v0.x); o[1] = f2bf(v0.y); o[2] = f2bf(v0.z); o[3] = f2bf(v0.w);
    o[4] = f2bf(v1.x); o[5] = f2bf(v1.y); o[6] = f2bf(v1.z); o[7] = f2bf(v1.w);
    *(short8*)(bB + ((size_t)j * NPOS + row) * 64 + sub * 8) = o;

    float s  = v0.x + v0.y + v0.z + v0.w + v1.x + v1.y + v1.z + v1.w;
    float sq = 0.f;
    sq = fmaf(v0.x, v0.x, sq); sq = fmaf(v0.y, v0.y, sq);
    sq = fmaf(v0.z, v0.z, sq); sq = fmaf(v0.w, v0.w, sq);
    sq = fmaf(v1.x, v1.x, sq); sq = fmaf(v1.y, v1.y, sq);
    sq = fmaf(v1.z, v1.z, sq); sq = fmaf(v1.w, v1.w, sq);
    float mx = fmaxf(fmaxf(fmaxf(v0.x, v0.y), fmaxf(v0.z, v0.w)),
                     fmaxf(fmaxf(v1.x, v1.y), fmaxf(v1.z, v1.w)));
    #pragma unroll
    for (int off = 1; off < 8; off <<= 1) {
        s  += __shfl_xor(s, off);
        sq += __shfl_xor(sq, off);
        mx  = fmaxf(mx, __shfl_xor(mx, off));
    }
    if (sub == 0) {
        float* sp = st + (size_t)row * 12 + j * 3;
        sp[0] = s * (1.f / 64.f);
        sp[1] = sqrtf(fmaxf(sq * (1.f / 64.f), 1e-8f));
        sp[2] = mx;
    }
}

// ---------------------------------------------------------------- K2: hid GEMM (unchanged control)
__global__ __launch_bounds__(512) void k_hid(const float* __restrict__ hidden,
                                             const short* __restrict__ WhT,
                                             float* __restrict__ hidT) {
    __shared__ float red[7][16][132];
    const int t    = threadIdx.x;
    const int lane = t & 63;
    const int wid  = __builtin_amdgcn_readfirstlane(t >> 6);   // 0..7
    const int quad = lane >> 4, lm = lane & 15;
    const int r0   = blockIdx.x * 16;

    f32x4 acc[8];
    #pragma unroll
    for (int nt = 0; nt < 8; ++nt) acc[nt] = (f32x4){0.f, 0.f, 0.f, 0.f};

    #pragma unroll
    for (int kk = 0; kk < 4; ++kk) {
        const int k0 = wid * 128 + kk * 32 + quad * 8;
        const float4 x0 = *(const float4*)(hidden + (size_t)(r0 + lm) * HIDN + k0);
        const float4 x1 = *(const float4*)(hidden + (size_t)(r0 + lm) * HIDN + k0 + 4);
        short8 a;
        a[0] = f2bf(x0.x); a[1] = f2bf(x0.y); a[2] = f2bf(x0.z); a[3] = f2bf(x0.w);
        a[4] = f2bf(x1.x); a[5] = f2bf(x1.y); a[6] = f2bf(x1.z); a[7] = f2bf(x1.w);
        #pragma unroll
        for (int nt = 0; nt < 8; ++nt) {
            const short8 bfr = *(const short8*)(WhT + (size_t)(nt * 16 + lm) * 1024 + k0);
            acc[nt] = __builtin_amdgcn_mfma_f32_16x16x32_bf16(a, bfr, acc[nt], 0, 0, 0);
        }
    }

    if (wid > 0) {
        #pragma unroll
        for (int nt = 0; nt < 8; ++nt)
            #pragma unroll
            for (int r = 0; r < 4; ++r)
                red[wid - 1][quad * 4 + r][nt * 16 + lm] = acc[nt][r];
    }
    __syncthreads();
    if (wid == 0) {
        #pragma unroll
        for (int nt = 0; nt < 8; ++nt)
            #pragma unroll
            for (int r = 0; r < 4; ++r) {
                float v = acc[nt][r];
                #pragma unroll
                for (int w = 0; w < 7; ++w) v += red[w][quad * 4 + r][nt * 16 + lm];
                hidT[(size_t)(r0 + quad * 4 + r) * TWO_D + nt * 16 + lm] = v;
            }
    }
}

// ---------------------------------------------------------------- shared epilogue
__device__ inline void gate_epilogue(const f32x4* acc, int quad, int lm, int bl,
                                     const float* __restrict__ b1,
                                     const float* __restrict__ W2,
                                     const float* __restrict__ b2,
                                     const float* __restrict__ eps_floor,
                                     const float* __restrict__ temp,
                                     const float* __restrict__ hidT,
                                     float* __restrict__ out) {
    const float4 b2v = *(const float4*)b2;
    float tcl[4]; float4 efl[4];
    #pragma unroll
    for (int r = 0; r < 4; ++r) {
        const int h = quad * 4 + r;
        tcl[r] = fminf(fmaxf(temp[h], 0.2f), 10.0f);
        efl[r] = *(const float4*)(eps_floor + h * 4);
    }
    float p[4][4];
    #pragma unroll
    for (int r = 0; r < 4; ++r)
        #pragma unroll
        for (int c = 0; c < 4; ++c) p[r][c] = 0.f;

    #pragma unroll
    for (int nt = 0; nt < 8; ++nt) {
        const int n = nt * 16 + lm;
        const float hv  = hidT[(size_t)bl * TWO_D + n];
        const float b1v = b1[n];
        const float4 w2v = *(const float4*)(W2 + n * 4);
        #pragma unroll
        for (int r = 0; r < 4; ++r) {
            const float x = acc[nt][r] + hv + b1v;
            const float g = 0.5f * x * (1.0f + erff(x * 0.7071067811865476f));
            p[r][0] = fmaf(g, w2v.x, p[r][0]);
            p[r][1] = fmaf(g, w2v.y, p[r][1]);
            p[r][2] = fmaf(g, w2v.z, p[r][2]);
            p[r][3] = fmaf(g, w2v.w, p[r][3]);
        }
    }
    #pragma unroll
    for (int r = 0; r < 4; ++r)
        #pragma unroll
        for (int c = 0; c < 4; ++c) {
            float v = p[r][c];
            v += __shfl_xor(v, 1); v += __shfl_xor(v, 2);
            v += __shfl_xor(v, 4); v += __shfl_xor(v, 8);
            p[r][c] = v;
        }
    #pragma unroll
    for (int r = 0; r < 4; ++r) {
        const float l0 = p[r][0] + b2v.x;
        const float l1 = p[r][1] + b2v.y;
        const float l2 = p[r][2] + b2v.z;
        const float l3 = p[r][3] + b2v.w;
        const float inv = 1.0f / tcl[r];
        const float m = fmaxf(fmaxf(l0, l1), fmaxf(l2, l3));
        float e0 = expf((l0 - m) * inv);
        float e1 = expf((l1 - m) * inv);
        float e2 = expf((l2 - m) * inv);
        float e3 = expf((l3 - m) * inv);
        const float rsum = 1.0f / (e0 + e1 + e2 + e3);
        float w0 = e0 * rsum, w1 = e1 * rsum, w2 = e2 * rsum, w3 = e3 * rsum;
        w0 = fmaxf(w0, fminf(fmaxf(efl[r].x, 1e-7f), 0.1f));
        w1 = fmaxf(w1, fminf(fmaxf(efl[r].y, 1e-7f), 0.1f));
        w2 = fmaxf(w2, fminf(fmaxf(efl[r].z, 1e-7f), 0.1f));
        w3 = fmaxf(w3, fminf(fmaxf(efl[r].w, 1e-7f), 0.1f));
        const float rs = 1.0f / (w0 + w1 + w2 + w3);
        if (lm == 0) {
            const int pos = bl * 16 + quad * 4 + r;
            float4 ov; ov.x = w0 * rs; ov.y = w1 * rs; ov.z = w2 * rs; ov.w = w3 * rs;
            *(float4*)(out + (size_t)pos * 4) = ov;
        }
    }
}

// stat-MFMA k-step shared by both mains
__device__ inline void stat_kstep(f32x4* acc, const float* stm, int quad, int lm,
                                  const short* __restrict__ wsT) {
    short8 sa;
    #pragma unroll
    for (int jj = 0; jj < 8; ++jj) {
        float v;
        if (jj < 4) v = (quad == 0) ? stm[jj] : ((quad == 1) ? stm[8 + jj] : 0.f);
        else        v = (quad == 0) ? stm[jj] : 0.f;
        sa[jj] = f2bf(v);
    }
    #pragma unroll
    for (int nt = 0; nt < 8; ++nt) {
        const short8 bfr = *(const short8*)(wsT + (size_t)(nt * 16 + lm) * 32 + quad * 8);
        acc[nt] = __builtin_amdgcn_mfma_f32_16x16x32_bf16(sa, bfr, acc[nt], 0, 0, 0);
    }
}

// ---------------------------------------------------------------- K3a: main, bf16-staged path
// 1024 blocks x 256 thr (4 waves, no LDS). Wave = one (b,l) m-tile.
__global__ __launch_bounds__(256) void k_main_bf(
    const short* __restrict__ bB, const float* __restrict__ st,
    const short* __restrict__ WbT, const short* __restrict__ wsT,
    const float* __restrict__ b1, const float* __restrict__ W2,
    const float* __restrict__ b2, const float* __restrict__ eps_floor,
    const float* __restrict__ temp, const float* __restrict__ hidT,
    float* __restrict__ out) {

    const int t    = threadIdx.x;
    const int lane = t & 63;
    const int wid  = __builtin_amdgcn_readfirstlane(t >> 6);
    const int quad = lane >> 4, lm = lane & 15;
    const int bx   = blockIdx.x;
    const int bxs  = (bx & 7) * 128 + (bx >> 3);    // XCD-contiguous
    const int bl   = bxs * 4 + wid;
    const int row  = bl * 16 + lm;

    f32x4 acc[8];
    #pragma unroll
    for (int nt = 0; nt < 8; ++nt) acc[nt] = (f32x4){0.f, 0.f, 0.f, 0.f};

    // per-row stats (same value across quads for a given lm)
    const float4 s0 = *(const float4*)(st + (size_t)row * 12);
    const float4 s1 = *(const float4*)(st + (size_t)row * 12 + 4);
    const float4 s2 = *(const float4*)(st + (size_t)row * 12 + 8);
    const float stm[12] = {s0.x, s0.y, s0.z, s0.w, s1.x, s1.y, s1.z, s1.w,
                           s2.x, s2.y, s2.z, s2.w};

    #pragma unroll
    for (int j = 0; j < 4; ++j) {
        #pragma unroll
        for (int half = 0; half < 2; ++half) {
            const short8 a = *(const short8*)(bB + ((size_t)j * NPOS + row) * 64
                                              + half * 32 + quad * 8);
            const int kg = j * 64 + half * 32 + quad * 8;
            #pragma unroll
            for (int nt = 0; nt < 8; ++nt) {
                const short8 bfr = *(const short8*)(WbT + (size_t)(nt * 16 + lm) * 256 + kg);
                acc[nt] = __builtin_amdgcn_mfma_f32_16x16x32_bf16(a, bfr, acc[nt], 0, 0, 0);
            }
        }
    }
    stat_kstep(acc, stm, quad, lm, wsT);
    gate_epilogue(acc, quad, lm, bl, b1, W2, b2, eps_floor, temp, hidT, out);
}

// ---------------------------------------------------------------- K3b: fallback fused-fp32 main
__global__ __launch_bounds__(256) void k_main_f32(
    const float* __restrict__ g0, const float* __restrict__ g1,
    const float* __restrict__ g2, const float* __restrict__ g3,
    const short* __restrict__ WbT, const short* __restrict__ wsT,
    const float* __restrict__ b1, const float* __restrict__ W2,
    const float* __restrict__ b2, const float* __restrict__ eps_floor,
    const float* __restrict__ temp, const float* __restrict__ hidT,
    float* __restrict__ out) {

    const int t    = threadIdx.x;
    const int lane = t & 63;
    const int wid  = __builtin_amdgcn_readfirstlane(t >> 6);
    const int quad = lane >> 4, lm = lane & 15;
    const int bl   = blockIdx.x * 4 + wid;

    f32x4 acc[8];
    #pragma unroll
    for (int nt = 0; nt < 8; ++nt) acc[nt] = (f32x4){0.f, 0.f, 0.f, 0.f};

    float stm[12];
    const float* const bjs[4] = {g0, g1, g2, g3};
    #pragma unroll
    for (int j = 0; j < 4; ++j) {
        const float* __restrict__ bj = bjs[j];
        float s = 0.f, sq = 0.f, mx = -INFINITY;
        #pragma unroll
        for (int half = 0; half < 2; ++half) {
            const int kc  = half * 32 + quad * 8;
            const int pos = bl * 16 + lm;
            const float4 x0 = *(const float4*)(bj + (size_t)pos * 64 + kc);
            const float4 x1 = *(const float4*)(bj + (size_t)pos * 64 + kc + 4);
            s  += x0.x + x0.y + x0.z + x0.w + x1.x + x1.y + x1.z + x1.w;
            sq  = fmaf(x0.x, x0.x, sq); sq = fmaf(x0.y, x0.y, sq);
            sq  = fmaf(x0.z, x0.z, sq); sq = fmaf(x0.w, x0.w, sq);
            sq  = fmaf(x1.x, x1.x, sq); sq = fmaf(x1.y, x1.y, sq);
            sq  = fmaf(x1.z, x1.z, sq); sq = fmaf(x1.w, x1.w, sq);
            mx  = fmaxf(mx, fmaxf(fmaxf(x0.x, x0.y), fmaxf(x0.z, x0.w)));
            mx  = fmaxf(mx, fmaxf(fmaxf(x1.x, x1.y), fmaxf(x1.z, x1.w)));
            short8 a;
            a[0] = f2bf(x0.x); a[1] = f2bf(x0.y); a[2] = f2bf(x0.z); a[3] = f2bf(x0.w);
            a[4] = f2bf(x1.x); a[5] = f2bf(x1.y); a[6] = f2bf(x1.z); a[7] = f2bf(x1.w);
            const int kg = j * 64 + half * 32 + quad * 8;
            #pragma unroll
            for (int nt = 0; nt < 8; ++nt) {
                const short8 bfr = *(const short8*)(WbT + (size_t)(nt * 16 + lm) * 256 + kg);
                acc[nt] = __builtin_amdgcn_mfma_f32_16x16x32_bf16(a, bfr, acc[nt], 0, 0, 0);
            }
        }
        float ss = s, qq = sq, mm = mx;
        ss += __shfl_xor(ss, 16); ss += __shfl_xor(ss, 32);
        qq += __shfl_xor(qq, 16); qq += __shfl_xor(qq, 32);
        mm  = fmaxf(mm, __shfl_xor(mm, 16)); mm = fmaxf(mm, __shfl_xor(mm, 32));
        stm[3 * j + 0] = ss * (1.f / 64.f);
        stm[3 * j + 1] = sqrtf(fmaxf(qq * (1.f / 64.f), 1e-8f));
        stm[3 * j + 2] = mm;
    }
    stat_kstep(acc, stm, quad, lm, wsT);
    gate_epilogue(acc, quad, lm, bl, b1, W2, b2, eps_floor, temp, hidT, out);
}

// ---------------------------------------------------------------- launch
extern "C" void kernel_launch(void* const* d_in, const int* in_sizes, int n_in,
                              void* d_out, int out_size, void* d_ws, size_t ws_size,
                              hipStream_t stream) {
    const float* hidden = (const float*)d_in[0];
    const float* br0    = (const float*)d_in[1];
    const float* br1    = (const float*)d_in[2];
    const float* br2    = (const float*)d_in[3];
    const float* br3    = (const float*)d_in[4];
    const float* W1     = (const float*)d_in[5];
    const float* b1     = (const float*)d_in[6];
    const float* W2     = (const float*)d_in[7];
    const float* b2     = (const float*)d_in[8];
    const float* eps    = (const float*)d_in[9];
    const float* temp   = (const float*)d_in[10];
    float* out = (float*)d_out;

    char* wsb = (char*)d_ws;
    float* hidT = (float*)(wsb);
    short* WhT  = (short*)(wsb + 2097152);
    short* WbT  = (short*)(wsb + 2359296);
    short* wsT  = (short*)(wsb + 2424832);
    short* bB   = (short*)(wsb + 2433024);
    float* st   = (float*)(wsb + 35987456);

    hipLaunchKernelGGL(k_prep, dim3(92),  dim3(256), 0, stream, W1, WhT, WbT, wsT);
    hipLaunchKernelGGL(k_hid,  dim3(256), dim3(512), 0, stream, hidden, WhT, hidT);
    if (ws_size >= WS_NEED) {
        hipLaunchKernelGGL(k_cvt,     dim3(8192), dim3(256), 0, stream,
                           br0, br1, br2, br3, bB, st);
        hipLaunchKernelGGL(k_main_bf, dim3(1024), dim3(256), 0, stream,
                           bB, st, WbT, wsT, b1, W2, b2, eps, temp, hidT, out);
    } else {
        hipLaunchKernelGGL(k_main_f32, dim3(1024), dim3(256), 0, stream,
                           br0, br1, br2, br3, WbT, wsT, b1, W2, b2, eps, temp,
                           hidT, out);
    }
}

// Round 6
// 139.048 us; speedup vs baseline: 1.3911x; 1.3911x over previous
//
#include <hip/hip_runtime.h>
#include <hip/hip_bf16.h>
#include <math.h>

// Problem constants (B=2, L=2048, H=16, D=64, HID=1024, NB=4)
#define NBL   4096      // B*L
#define NPOS  65536     // B*L*H
#define TWO_D 128
#define HIDN  1024

typedef __attribute__((ext_vector_type(8))) short short8;  // 8 bf16 (4 VGPRs)
typedef __attribute__((ext_vector_type(4))) float f32x4;   // MFMA accumulator
typedef __attribute__((ext_vector_type(4))) unsigned int uint4v;

// fp32 -> bf16 RNE (scalar, prep only)
__device__ inline short f2bf(float f) {
    union { float f; unsigned u; } v; v.f = f;
    unsigned r = (v.u + 0x7FFFu + ((v.u >> 16) & 1u)) >> 16;
    return (short)r;
}
// packed fp32x2 -> bf16x2 (hardware v_cvt_pk_bf16_f32)
__device__ inline unsigned pkbf(float x, float y) {
    __hip_bfloat162 h = __float22bfloat162_rn(make_float2(x, y));
    union { __hip_bfloat162 h; unsigned u; } c; c.h = h;
    return c.u;
}
// fast GELU (tanh form), ~8 VALU: x * sigmoid(1.5957691*(x + 0.044715 x^3))
__device__ inline float gelu_fast(float x) {
    const float x2 = x * x;
    const float u  = x * fmaf(x2, 0.044715f, 1.0f) * 1.5957691216057308f;
    const float e  = __expf(-u);
    return x * __builtin_amdgcn_rcpf(1.0f + e);
}

// ws layout (bytes):
//   hidT : float [4096][128]          @ 0          (2,097,152)
//   hP   : float [4][4096][128]       @ 2,097,152  (8,388,608)
//   WhS  : bf16  [4][128][256]        @ 10,485,760 (262,144)   (K-quarter sliced, transposed)
//   WbT  : bf16  [128][256]           @ 10,747,904 (65,536)
//   wsT  : bf16  [128][32]            @ 10,813,440 (8,192)

// ---------------------------------------------------------------- K0: weight prep
__global__ __launch_bounds__(256) void k_prep(const float* __restrict__ W1,
                                              short* __restrict__ WhS,
                                              short* __restrict__ WbT,
                                              short* __restrict__ wsT) {
    __shared__ float lds[16][129];
    __shared__ float acc2[128];
    const int b = blockIdx.x, t = threadIdx.x;
    if (b < 80) {
        int srcRow0; short* dst; int kofs, kD;
        if (b < 64) {            // hid rows -> sliced layout WhS[q][n][kq]
            srcRow0 = b * 16;
            const int q = b >> 4;            // K-quarter
            dst  = WhS + q * (128 * 256);
            kofs = (b * 16) & 255;
            kD   = 256;
        } else {
            srcRow0 = 1792 + (b - 64) * 16;
            dst  = WbT;
            kofs = (b - 64) * 16;
            kD   = 256;
        }
        #pragma unroll
        for (int i = 0; i < 8; ++i) {
            const int idx = i * 256 + t;
            const int row = idx >> 7, col = idx & 127;
            lds[row][col] = W1[(size_t)(srcRow0 + row) * TWO_D + col];   // coalesced
        }
        __syncthreads();
        #pragma unroll
        for (int i = 0; i < 8; ++i) {
            const int idx = i * 256 + t;
            const int n = idx >> 4, k = idx & 15;
            dst[(size_t)n * kD + kofs + k] = f2bf(lds[k][n]);
        }
    } else {
        const int i = b - 80;                       // 0..11
        const int j = i / 3, sx = i - 3 * j;
        const int base = HIDN + j * 192 + sx * 64;
        const int n = t & 127, dh = t >> 7;
        float s = 0.f;
        for (int d = 0; d < 32; ++d)
            s += W1[(size_t)(base + dh * 32 + d) * TWO_D + n];  // coalesced
        if (dh) acc2[n] = s;
        __syncthreads();
        if (!dh) {
            wsT[n * 32 + i] = f2bf(s + acc2[n]);
            if (i == 0)
                for (int p = 12; p < 32; ++p) wsT[n * 32 + p] = (short)0;
        }
    }
}

// ---------------------------------------------------------------- K1: hid GEMM partials
// grid 256: q = bx&3 (K-quarter), mg = bx>>2 (group of 4 m-tiles).
// block 256 thr = 4 waves; wave w = m-tile mg*4+w. WhS[q] staged in LDS.
__global__ __launch_bounds__(256) void k_hid(const float* __restrict__ hidden,
                                             const short* __restrict__ WhS,
                                             float* __restrict__ hP) {
    __shared__ short wb[128 * 264];                 // pitch 264 (2-way max)
    const int t    = threadIdx.x;
    const int lane = t & 63;
    const int w    = __builtin_amdgcn_readfirstlane(t >> 6);   // 0..3
    const int quad = lane >> 4, lm = lane & 15;
    const int q    = blockIdx.x & 3;
    const int mg   = blockIdx.x >> 2;
    const int r0   = (mg * 4 + w) * 16;

    const short* __restrict__ src = WhS + (size_t)q * (128 * 256);
    #pragma unroll
    for (int i = 0; i < 16; ++i) {
        const int idx = i * 256 + t;                // chunk of 8 shorts
        const int row = idx >> 5, col = (idx & 31) * 8;
        *(short8*)(wb + row * 264 + col) = *(const short8*)(src + row * 256 + col);
    }
    __syncthreads();

    f32x4 acc[8];
    #pragma unroll
    for (int nt = 0; nt < 8; ++nt) acc[nt] = (f32x4){0.f, 0.f, 0.f, 0.f};

    #pragma unroll
    for (int kk = 0; kk < 8; ++kk) {
        const int kc = kk * 32 + quad * 8;          // within quarter
        const int kG = q * 256 + kc;
        const float4 x0 = *(const float4*)(hidden + (size_t)(r0 + lm) * HIDN + kG);
        const float4 x1 = *(const float4*)(hidden + (size_t)(r0 + lm) * HIDN + kG + 4);
        union { short8 s; uint4v u; } a;
        a.u = (uint4v){pkbf(x0.x, x0.y), pkbf(x0.z, x0.w),
                       pkbf(x1.x, x1.y), pkbf(x1.z, x1.w)};
        #pragma unroll
        for (int nt = 0; nt < 8; ++nt) {
            const short8 bfr = *(const short8*)(wb + (nt * 16 + lm) * 264 + kc);
            acc[nt] = __builtin_amdgcn_mfma_f32_16x16x32_bf16(a.s, bfr, acc[nt], 0, 0, 0);
        }
    }

    float* __restrict__ dst = hP + (size_t)q * NBL * TWO_D;
    #pragma unroll
    for (int nt = 0; nt < 8; ++nt)
        #pragma unroll
        for (int r = 0; r < 4; ++r)
            dst[(size_t)(r0 + quad * 4 + r) * TWO_D + nt * 16 + lm] = acc[nt][r];
}

// ---------------------------------------------------------------- K2: reduce partials
__global__ __launch_bounds__(256) void k_hidred(float* __restrict__ hidT,
                                                const float* __restrict__ hP) {
    const int i = blockIdx.x * 256 + threadIdx.x;   // < 524288
    hidT[i] = hP[i] + hP[524288 + i] + hP[2 * 524288 + i] + hP[3 * 524288 + i];
}

// ---------------------------------------------------------------- K3: main fused kernel
// grid 512 x 512 thr (8 waves). Wave = one (b,l) m-tile (16 heads).
// WbT/wsT/W2/b1 staged in LDS; A read fp32 direct + stats inline.
__global__ __launch_bounds__(512) void k_main(
    const float* __restrict__ g0, const float* __restrict__ g1,
    const float* __restrict__ g2, const float* __restrict__ g3,
    const short* __restrict__ WbT, const short* __restrict__ wsT,
    const float* __restrict__ b1, const float* __restrict__ W2,
    const float* __restrict__ b2, const float* __restrict__ eps_floor,
    const float* __restrict__ temp, const float* __restrict__ hidT,
    float* __restrict__ out) {

    __shared__ short wb[128 * 264];                 // 67,584 B
    __shared__ short wss[128 * 40];                 // 10,240 B
    __shared__ float w2s[512];                      //  2,048 B
    __shared__ float b1s[128];                      //    512 B

    const int t    = threadIdx.x;
    const int lane = t & 63;
    const int w    = __builtin_amdgcn_readfirstlane(t >> 6);   // 0..7
    const int quad = lane >> 4, lm = lane & 15;
    const int bl   = blockIdx.x * 8 + w;            // (b,l) index = m-tile
    const int pos0 = bl * 16;

    // ---- cooperative staging
    #pragma unroll
    for (int i = 0; i < 8; ++i) {
        const int idx = i * 512 + t;                // 4096 chunks of 8 shorts
        const int row = idx >> 5, col = (idx & 31) * 8;
        *(short8*)(wb + row * 264 + col) = *(const short8*)(WbT + row * 256 + col);
    }
    {
        const int row = t >> 2, col = (t & 3) * 8;  // 512 chunks of 8 shorts
        *(short8*)(wss + row * 40 + col) = *(const short8*)(wsT + row * 32 + col);
        w2s[t] = W2[t];
        if (t < 128) b1s[t] = b1[t];
    }
    __syncthreads();

    f32x4 acc[8];
    #pragma unroll
    for (int nt = 0; nt < 8; ++nt) acc[nt] = (f32x4){0.f, 0.f, 0.f, 0.f};

    float stm[12];
    const float* const bjs[4] = {g0, g1, g2, g3};
    #pragma unroll
    for (int j = 0; j < 4; ++j) {
        const float* __restrict__ bj = bjs[j];
        float s = 0.f, sq = 0.f, mx = -INFINITY;
        #pragma unroll
        for (int half = 0; half < 2; ++half) {
            const int kc = half * 32 + quad * 8;
            const float4 x0 = *(const float4*)(bj + (size_t)(pos0 + lm) * 64 + kc);
            const float4 x1 = *(const float4*)(bj + (size_t)(pos0 + lm) * 64 + kc + 4);
            s  += x0.x + x0.y + x0.z + x0.w + x1.x + x1.y + x1.z + x1.w;
            sq  = fmaf(x0.x, x0.x, sq); sq = fmaf(x0.y, x0.y, sq);
            sq  = fmaf(x0.z, x0.z, sq); sq = fmaf(x0.w, x0.w, sq);
            sq  = fmaf(x1.x, x1.x, sq); sq = fmaf(x1.y, x1.y, sq);
            sq  = fmaf(x1.z, x1.z, sq); sq = fmaf(x1.w, x1.w, sq);
            mx  = fmaxf(mx, fmaxf(fmaxf(x0.x, x0.y), fmaxf(x0.z, x0.w)));
            mx  = fmaxf(mx, fmaxf(fmaxf(x1.x, x1.y), fmaxf(x1.z, x1.w)));
            union { short8 s; uint4v u; } a;
            a.u = (uint4v){pkbf(x0.x, x0.y), pkbf(x0.z, x0.w),
                           pkbf(x1.x, x1.y), pkbf(x1.z, x1.w)};
            const int kg = j * 64 + half * 32 + quad * 8;
            #pragma unroll
            for (int nt = 0; nt < 8; ++nt) {
                const short8 bfr = *(const short8*)(wb + (nt * 16 + lm) * 264 + kg);
                acc[nt] = __builtin_amdgcn_mfma_f32_16x16x32_bf16(a.s, bfr, acc[nt], 0, 0, 0);
            }
        }
        float ss = s, qq = sq, mm = mx;
        ss += __shfl_xor(ss, 16); ss += __shfl_xor(ss, 32);
        qq += __shfl_xor(qq, 16); qq += __shfl_xor(qq, 32);
        mm  = fmaxf(mm, __shfl_xor(mm, 16)); mm = fmaxf(mm, __shfl_xor(mm, 32));
        stm[3 * j + 0] = ss * (1.f / 64.f);
        stm[3 * j + 1] = sqrtf(fmaxf(qq * (1.f / 64.f), 1e-8f));
        stm[3 * j + 2] = mm;
    }

    // stat k-step via wsT (LDS)
    {
        short8 sa;
        #pragma unroll
        for (int jj = 0; jj < 8; ++jj) {
            float v;
            if (jj < 4) v = (quad == 0) ? stm[jj] : ((quad == 1) ? stm[8 + jj] : 0.f);
            else        v = (quad == 0) ? stm[jj] : 0.f;
            sa[jj] = f2bf(v);
        }
        #pragma unroll
        for (int nt = 0; nt < 8; ++nt) {
            const short8 bfr = *(const short8*)(wss + (nt * 16 + lm) * 40 + quad * 8);
            acc[nt] = __builtin_amdgcn_mfma_f32_16x16x32_bf16(sa, bfr, acc[nt], 0, 0, 0);
        }
    }

    // ---- epilogue: + hidT + b1, fast GELU, W2 partials, reduce, softmax
    const float4 b2v = *(const float4*)b2;
    float tcl[4]; float4 efl[4];
    #pragma unroll
    for (int r = 0; r < 4; ++r) {
        const int h = quad * 4 + r;
        tcl[r] = fminf(fmaxf(temp[h], 0.2f), 10.0f);
        efl[r] = *(const float4*)(eps_floor + h * 4);
    }

    float p[4][4];
    #pragma unroll
    for (int r = 0; r < 4; ++r)
        #pragma unroll
        for (int c = 0; c < 4; ++c) p[r][c] = 0.f;

    #pragma unroll
    for (int nt = 0; nt < 8; ++nt) {
        const int n = nt * 16 + lm;
        const float hv  = hidT[(size_t)bl * TWO_D + n];
        const float b1v = b1s[n];
        const float4 w2v = *(const float4*)(w2s + n * 4);
        #pragma unroll
        for (int r = 0; r < 4; ++r) {
            const float x = acc[nt][r] + hv + b1v;
            const float g = gelu_fast(x);
            p[r][0] = fmaf(g, w2v.x, p[r][0]);
            p[r][1] = fmaf(g, w2v.y, p[r][1]);
            p[r][2] = fmaf(g, w2v.z, p[r][2]);
            p[r][3] = fmaf(g, w2v.w, p[r][3]);
        }
    }
    #pragma unroll
    for (int r = 0; r < 4; ++r)
        #pragma unroll
        for (int c = 0; c < 4; ++c) {
            float v = p[r][c];
            v += __shfl_xor(v, 1); v += __shfl_xor(v, 2);
            v += __shfl_xor(v, 4); v += __shfl_xor(v, 8);
            p[r][c] = v;
        }

    #pragma unroll
    for (int r = 0; r < 4; ++r) {
        const float l0 = p[r][0] + b2v.x;
        const float l1 = p[r][1] + b2v.y;
        const float l2 = p[r][2] + b2v.z;
        const float l3 = p[r][3] + b2v.w;
        const float inv = 1.0f / tcl[r];
        const float m = fmaxf(fmaxf(l0, l1), fmaxf(l2, l3));
        float e0 = __expf((l0 - m) * inv);
        float e1 = __expf((l1 - m) * inv);
        float e2 = __expf((l2 - m) * inv);
        float e3 = __expf((l3 - m) * inv);
        const float rsum = 1.0f / (e0 + e1 + e2 + e3);
        float w0 = e0 * rsum, w1 = e1 * rsum, w2 = e2 * rsum, w3 = e3 * rsum;
        w0 = fmaxf(w0, fminf(fmaxf(efl[r].x, 1e-7f), 0.1f));
        w1 = fmaxf(w1, fminf(fmaxf(efl[r].y, 1e-7f), 0.1f));
        w2 = fmaxf(w2, fminf(fmaxf(efl[r].z, 1e-7f), 0.1f));
        w3 = fmaxf(w3, fminf(fmaxf(efl[r].w, 1e-7f), 0.1f));
        const float rs = 1.0f / (w0 + w1 + w2 + w3);
        if (lm == 0) {
            const int pos = pos0 + quad * 4 + r;
            float4 ov; ov.x = w0 * rs; ov.y = w1 * rs; ov.z = w2 * rs; ov.w = w3 * rs;
            *(float4*)(out + (size_t)pos * 4) = ov;
        }
    }
}

// ---------------------------------------------------------------- launch
extern "C" void kernel_launch(void* const* d_in, const int* in_sizes, int n_in,
                              void* d_out, int out_size, void* d_ws, size_t ws_size,
                              hipStream_t stream) {
    const float* hidden = (const float*)d_in[0];
    const float* br0    = (const float*)d_in[1];
    const float* br1    = (const float*)d_in[2];
    const float* br2    = (const float*)d_in[3];
    const float* br3    = (const float*)d_in[4];
    const float* W1     = (const float*)d_in[5];
    const float* b1     = (const float*)d_in[6];
    const float* W2     = (const float*)d_in[7];
    const float* b2     = (const float*)d_in[8];
    const float* eps    = (const float*)d_in[9];
    const float* temp   = (const float*)d_in[10];
    float* out = (float*)d_out;

    char* wsb = (char*)d_ws;
    float* hidT = (float*)(wsb);
    float* hP   = (float*)(wsb + 2097152);
    short* WhS  = (short*)(wsb + 10485760);
    short* WbT  = (short*)(wsb + 10747904);
    short* wsT  = (short*)(wsb + 10813440);

    hipLaunchKernelGGL(k_prep,   dim3(92),   dim3(256), 0, stream, W1, WhS, WbT, wsT);
    hipLaunchKernelGGL(k_hid,    dim3(256),  dim3(256), 0, stream, hidden, WhS, hP);
    hipLaunchKernelGGL(k_hidred, dim3(2048), dim3(256), 0, stream, hidT, hP);
    hipLaunchKernelGGL(k_main,   dim3(512),  dim3(512), 0, stream,
                       br0, br1, br2, br3, WbT, wsT, b1, W2, b2, eps, temp,
                       hidT, out);
}

// Round 7
// 137.839 us; speedup vs baseline: 1.4033x; 1.0088x over previous
//
#include <hip/hip_runtime.h>
#include <hip/hip_bf16.h>
#include <math.h>

// Problem constants (B=2, L=2048, H=16, D=64, HID=1024, NB=4)
#define NBL   4096      // B*L
#define NPOS  65536     // B*L*H
#define TWO_D 128
#define HIDN  1024

typedef __attribute__((ext_vector_type(8))) short short8;  // 8 bf16 (4 VGPRs)
typedef __attribute__((ext_vector_type(4))) float f32x4;   // MFMA accumulator
typedef __attribute__((ext_vector_type(4))) unsigned int uint4v;

// fp32 -> bf16 RNE (scalar, prep only)
__device__ inline short f2bf(float f) {
    union { float f; unsigned u; } v; v.f = f;
    unsigned r = (v.u + 0x7FFFu + ((v.u >> 16) & 1u)) >> 16;
    return (short)r;
}
// packed fp32x2 -> bf16x2 (hardware v_cvt_pk_bf16_f32)
__device__ inline unsigned pkbf(float x, float y) {
    __hip_bfloat162 h = __float22bfloat162_rn(make_float2(x, y));
    union { __hip_bfloat162 h; unsigned u; } c; c.h = h;
    return c.u;
}
// fast GELU (tanh form): x * sigmoid(1.5957691*(x + 0.044715 x^3))
__device__ inline float gelu_fast(float x) {
    const float x2 = x * x;
    const float u  = x * fmaf(x2, 0.044715f, 1.0f) * 1.5957691216057308f;
    const float e  = __expf(-u);
    return x * __builtin_amdgcn_rcpf(1.0f + e);
}

// ws layout (bytes):
//   hP   : float [4][4096][128]       @ 0          (8,388,608)   hid K-quarter partials
//   WhS  : bf16  [4][128][256]        @ 8,388,608  (262,144)
//   WbT  : bf16  [128][256]           @ 8,650,752  (65,536)
//   wsT  : bf16  [128][32]            @ 8,716,288  (8,192)

// ---------------------------------------------------------------- K0: weight prep
__global__ __launch_bounds__(256) void k_prep(const float* __restrict__ W1,
                                              short* __restrict__ WhS,
                                              short* __restrict__ WbT,
                                              short* __restrict__ wsT) {
    __shared__ float lds[16][129];
    __shared__ float acc2[128];
    const int b = blockIdx.x, t = threadIdx.x;
    if (b < 80) {
        int srcRow0; short* dst; int kofs;
        if (b < 64) {            // hid rows -> sliced layout WhS[q][n][kq]
            srcRow0 = b * 16;
            const int q = b >> 4;            // K-quarter
            dst  = WhS + q * (128 * 256);
            kofs = (b * 16) & 255;
        } else {
            srcRow0 = 1792 + (b - 64) * 16;
            dst  = WbT;
            kofs = (b - 64) * 16;
        }
        #pragma unroll
        for (int i = 0; i < 8; ++i) {
            const int idx = i * 256 + t;
            const int row = idx >> 7, col = idx & 127;
            lds[row][col] = W1[(size_t)(srcRow0 + row) * TWO_D + col];   // coalesced
        }
        __syncthreads();
        #pragma unroll
        for (int i = 0; i < 8; ++i) {
            const int idx = i * 256 + t;
            const int n = idx >> 4, k = idx & 15;
            dst[(size_t)n * 256 + kofs + k] = f2bf(lds[k][n]);
        }
    } else {
        const int i = b - 80;                       // 0..11
        const int j = i / 3, sx = i - 3 * j;
        const int base = HIDN + j * 192 + sx * 64;
        const int n = t & 127, dh = t >> 7;
        float s = 0.f;
        for (int d = 0; d < 32; ++d)
            s += W1[(size_t)(base + dh * 32 + d) * TWO_D + n];  // coalesced
        if (dh) acc2[n] = s;
        __syncthreads();
        if (!dh) {
            wsT[n * 32 + i] = f2bf(s + acc2[n]);
            if (i == 0)
                for (int p = 12; p < 32; ++p) wsT[n * 32 + p] = (short)0;
        }
    }
}

// ---------------------------------------------------------------- K1: hid GEMM partials
// grid 256: q = bx&3 (K-quarter), mg = bx>>2 (group of 4 m-tiles).
// block 256 thr = 4 waves; wave w = m-tile mg*4+w. WhS[q] staged in LDS.
__global__ __launch_bounds__(256) void k_hid(const float* __restrict__ hidden,
                                             const short* __restrict__ WhS,
                                             float* __restrict__ hP) {
    __shared__ short wb[128 * 264];                 // pitch 264 (67.6 KB)
    const int t    = threadIdx.x;
    const int lane = t & 63;
    const int w    = __builtin_amdgcn_readfirstlane(t >> 6);   // 0..3
    const int quad = lane >> 4, lm = lane & 15;
    const int q    = blockIdx.x & 3;
    const int mg   = blockIdx.x >> 2;
    const int r0   = (mg * 4 + w) * 16;

    const short* __restrict__ src = WhS + (size_t)q * (128 * 256);
    #pragma unroll
    for (int i = 0; i < 16; ++i) {
        const int idx = i * 256 + t;                // chunk of 8 shorts
        const int row = idx >> 5, col = (idx & 31) * 8;
        *(short8*)(wb + row * 264 + col) = *(const short8*)(src + row * 256 + col);
    }
    __syncthreads();

    f32x4 acc[8];
    #pragma unroll
    for (int nt = 0; nt < 8; ++nt) acc[nt] = (f32x4){0.f, 0.f, 0.f, 0.f};

    #pragma unroll
    for (int kk = 0; kk < 8; ++kk) {
        const int kc = kk * 32 + quad * 8;          // within quarter
        const int kG = q * 256 + kc;
        const float4 x0 = *(const float4*)(hidden + (size_t)(r0 + lm) * HIDN + kG);
        const float4 x1 = *(const float4*)(hidden + (size_t)(r0 + lm) * HIDN + kG + 4);
        union { short8 s; uint4v u; } a;
        a.u = (uint4v){pkbf(x0.x, x0.y), pkbf(x0.z, x0.w),
                       pkbf(x1.x, x1.y), pkbf(x1.z, x1.w)};
        #pragma unroll
        for (int nt = 0; nt < 8; ++nt) {
            const short8 bfr = *(const short8*)(wb + (nt * 16 + lm) * 264 + kc);
            acc[nt] = __builtin_amdgcn_mfma_f32_16x16x32_bf16(a.s, bfr, acc[nt], 0, 0, 0);
        }
    }

    float* __restrict__ dst = hP + (size_t)q * NBL * TWO_D;
    #pragma unroll
    for (int nt = 0; nt < 8; ++nt)
        #pragma unroll
        for (int r = 0; r < 4; ++r)
            dst[(size_t)(r0 + quad * 4 + r) * TWO_D + nt * 16 + lm] = acc[nt][r];
}

// ---------------------------------------------------------------- K2: main fused kernel
// grid 512 x 512 thr (8 waves). Wave = one (b,l) m-tile (16 heads).
// WbT/W2/b1 staged in LDS (70.1 KB -> 2 blocks/CU); wsT read from L2.
// Epilogue sums the 4 hid partials directly (k_hidred folded in).
__global__ __launch_bounds__(512, 4) void k_main(
    const float* __restrict__ g0, const float* __restrict__ g1,
    const float* __restrict__ g2, const float* __restrict__ g3,
    const short* __restrict__ WbT, const short* __restrict__ wsT,
    const float* __restrict__ b1, const float* __restrict__ W2,
    const float* __restrict__ b2, const float* __restrict__ eps_floor,
    const float* __restrict__ temp, const float* __restrict__ hP,
    float* __restrict__ out) {

    __shared__ short wb[128 * 264];                 // 67,584 B
    __shared__ float w2s[512];                      //  2,048 B
    __shared__ float b1s[128];                      //    512 B

    const int t    = threadIdx.x;
    const int lane = t & 63;
    const int w    = __builtin_amdgcn_readfirstlane(t >> 6);   // 0..7
    const int quad = lane >> 4, lm = lane & 15;
    const int bl   = blockIdx.x * 8 + w;            // (b,l) index = m-tile
    const int pos0 = bl * 16;

    // ---- cooperative staging
    #pragma unroll
    for (int i = 0; i < 8; ++i) {
        const int idx = i * 512 + t;                // 4096 chunks of 8 shorts
        const int row = idx >> 5, col = (idx & 31) * 8;
        *(short8*)(wb + row * 264 + col) = *(const short8*)(WbT + row * 256 + col);
    }
    w2s[t] = W2[t];
    if (t < 128) b1s[t] = b1[t];
    __syncthreads();

    f32x4 acc[8];
    #pragma unroll
    for (int nt = 0; nt < 8; ++nt) acc[nt] = (f32x4){0.f, 0.f, 0.f, 0.f};

    float stm[12];
    const float* const bjs[4] = {g0, g1, g2, g3};
    #pragma unroll
    for (int j = 0; j < 4; ++j) {
        const float* __restrict__ bj = bjs[j];
        float s = 0.f, sq = 0.f, mx = -INFINITY;
        #pragma unroll
        for (int half = 0; half < 2; ++half) {
            const int kc = half * 32 + quad * 8;
            const float4 x0 = *(const float4*)(bj + (size_t)(pos0 + lm) * 64 + kc);
            const float4 x1 = *(const float4*)(bj + (size_t)(pos0 + lm) * 64 + kc + 4);
            s  += x0.x + x0.y + x0.z + x0.w + x1.x + x1.y + x1.z + x1.w;
            sq  = fmaf(x0.x, x0.x, sq); sq = fmaf(x0.y, x0.y, sq);
            sq  = fmaf(x0.z, x0.z, sq); sq = fmaf(x0.w, x0.w, sq);
            sq  = fmaf(x1.x, x1.x, sq); sq = fmaf(x1.y, x1.y, sq);
            sq  = fmaf(x1.z, x1.z, sq); sq = fmaf(x1.w, x1.w, sq);
            mx  = fmaxf(mx, fmaxf(fmaxf(x0.x, x0.y), fmaxf(x0.z, x0.w)));
            mx  = fmaxf(mx, fmaxf(fmaxf(x1.x, x1.y), fmaxf(x1.z, x1.w)));
            union { short8 s; uint4v u; } a;
            a.u = (uint4v){pkbf(x0.x, x0.y), pkbf(x0.z, x0.w),
                           pkbf(x1.x, x1.y), pkbf(x1.z, x1.w)};
            const int kg = j * 64 + half * 32 + quad * 8;
            #pragma unroll
            for (int nt = 0; nt < 8; ++nt) {
                const short8 bfr = *(const short8*)(wb + (nt * 16 + lm) * 264 + kg);
                acc[nt] = __builtin_amdgcn_mfma_f32_16x16x32_bf16(a.s, bfr, acc[nt], 0, 0, 0);
            }
        }
        float ss = s, qq = sq, mm = mx;
        ss += __shfl_xor(ss, 16); ss += __shfl_xor(ss, 32);
        qq += __shfl_xor(qq, 16); qq += __shfl_xor(qq, 32);
        mm  = fmaxf(mm, __shfl_xor(mm, 16)); mm = fmaxf(mm, __shfl_xor(mm, 32));
        stm[3 * j + 0] = ss * (1.f / 64.f);
        stm[3 * j + 1] = sqrtf(fmaxf(qq * (1.f / 64.f), 1e-8f));
        stm[3 * j + 2] = mm;
    }

    // stat k-step via wsT (L2-resident global)
    {
        short8 sa;
        #pragma unroll
        for (int jj = 0; jj < 8; ++jj) {
            float v;
            if (jj < 4) v = (quad == 0) ? stm[jj] : ((quad == 1) ? stm[8 + jj] : 0.f);
            else        v = (quad == 0) ? stm[jj] : 0.f;
            sa[jj] = f2bf(v);
        }
        #pragma unroll
        for (int nt = 0; nt < 8; ++nt) {
            const short8 bfr = *(const short8*)(wsT + (size_t)(nt * 16 + lm) * 32 + quad * 8);
            acc[nt] = __builtin_amdgcn_mfma_f32_16x16x32_bf16(sa, bfr, acc[nt], 0, 0, 0);
        }
    }

    // ---- epilogue: + hid partials + b1, fast GELU, W2 partials, reduce, softmax
    const float4 b2v = *(const float4*)b2;
    float tcl[4]; float4 efl[4];
    #pragma unroll
    for (int r = 0; r < 4; ++r) {
        const int h = quad * 4 + r;
        tcl[r] = fminf(fmaxf(temp[h], 0.2f), 10.0f);
        efl[r] = *(const float4*)(eps_floor + h * 4);
    }

    float p[4][4];
    #pragma unroll
    for (int r = 0; r < 4; ++r)
        #pragma unroll
        for (int c = 0; c < 4; ++c) p[r][c] = 0.f;

    #pragma unroll
    for (int nt = 0; nt < 8; ++nt) {
        const int n = nt * 16 + lm;
        const size_t hi = (size_t)bl * TWO_D + n;
        const float hv = hP[hi] + hP[524288 + hi] + hP[2 * 524288 + hi]
                       + hP[3 * 524288 + hi];
        const float b1v = b1s[n];
        const float4 w2v = *(const float4*)(w2s + n * 4);
        #pragma unroll
        for (int r = 0; r < 4; ++r) {
            const float x = acc[nt][r] + hv + b1v;
            const float g = gelu_fast(x);
            p[r][0] = fmaf(g, w2v.x, p[r][0]);
            p[r][1] = fmaf(g, w2v.y, p[r][1]);
            p[r][2] = fmaf(g, w2v.z, p[r][2]);
            p[r][3] = fmaf(g, w2v.w, p[r][3]);
        }
    }
    #pragma unroll
    for (int r = 0; r < 4; ++r)
        #pragma unroll
        for (int c = 0; c < 4; ++c) {
            float v = p[r][c];
            v += __shfl_xor(v, 1); v += __shfl_xor(v, 2);
            v += __shfl_xor(v, 4); v += __shfl_xor(v, 8);
            p[r][c] = v;
        }

    #pragma unroll
    for (int r = 0; r < 4; ++r) {
        const float l0 = p[r][0] + b2v.x;
        const float l1 = p[r][1] + b2v.y;
        const float l2 = p[r][2] + b2v.z;
        const float l3 = p[r][3] + b2v.w;
        const float inv = 1.0f / tcl[r];
        const float m = fmaxf(fmaxf(l0, l1), fmaxf(l2, l3));
        float e0 = __expf((l0 - m) * inv);
        float e1 = __expf((l1 - m) * inv);
        float e2 = __expf((l2 - m) * inv);
        float e3 = __expf((l3 - m) * inv);
        const float rsum = 1.0f / (e0 + e1 + e2 + e3);
        float w0 = e0 * rsum, w1 = e1 * rsum, w2 = e2 * rsum, w3 = e3 * rsum;
        w0 = fmaxf(w0, fminf(fmaxf(efl[r].x, 1e-7f), 0.1f));
        w1 = fmaxf(w1, fminf(fmaxf(efl[r].y, 1e-7f), 0.1f));
        w2 = fmaxf(w2, fminf(fmaxf(efl[r].z, 1e-7f), 0.1f));
        w3 = fmaxf(w3, fminf(fmaxf(efl[r].w, 1e-7f), 0.1f));
        const float rs = 1.0f / (w0 + w1 + w2 + w3);
        if (lm == 0) {
            const int pos = pos0 + quad * 4 + r;
            float4 ov; ov.x = w0 * rs; ov.y = w1 * rs; ov.z = w2 * rs; ov.w = w3 * rs;
            *(float4*)(out + (size_t)pos * 4) = ov;
        }
    }
}

// ---------------------------------------------------------------- launch
extern "C" void kernel_launch(void* const* d_in, const int* in_sizes, int n_in,
                              void* d_out, int out_size, void* d_ws, size_t ws_size,
                              hipStream_t stream) {
    const float* hidden = (const float*)d_in[0];
    const float* br0    = (const float*)d_in[1];
    const float* br1    = (const float*)d_in[2];
    const float* br2    = (const float*)d_in[3];
    const float* br3    = (const float*)d_in[4];
    const float* W1     = (const float*)d_in[5];
    const float* b1     = (const float*)d_in[6];
    const float* W2     = (const float*)d_in[7];
    const float* b2     = (const float*)d_in[8];
    const float* eps    = (const float*)d_in[9];
    const float* temp   = (const float*)d_in[10];
    float* out = (float*)d_out;

    char* wsb = (char*)d_ws;
    float* hP  = (float*)(wsb);
    short* WhS = (short*)(wsb + 8388608);
    short* WbT = (short*)(wsb + 8650752);
    short* wsT = (short*)(wsb + 8716288);

    hipLaunchKernelGGL(k_prep, dim3(92),  dim3(256), 0, stream, W1, WhS, WbT, wsT);
    hipLaunchKernelGGL(k_hid,  dim3(256), dim3(256), 0, stream, hidden, WhS, hP);
    hipLaunchKernelGGL(k_main, dim3(512), dim3(512), 0, stream,
                       br0, br1, br2, br3, WbT, wsT, b1, W2, b2, eps, temp,
                       hP, out);
}